// Round 1
// baseline (830.096 us; speedup 1.0000x reference)
//
#include <hip/hip_runtime.h>

#define B_ 4
#define H_ 4
#define N_ 2048
#define D_ 64
#define TI 8
#define NT 256

__global__ __launch_bounds__(NT, 2)
void lg_attn(const float* __restrict__ q,
             const float* __restrict__ k,
             const float* __restrict__ v,
             const int* __restrict__ mask,
             float* __restrict__ out,
             float* __restrict__ attn)
{
    __shared__ float sc[TI * N_];   // 64 KB: score/prob tile, reused as reduce scratch
    __shared__ float red[8];

    const int tid  = threadIdx.x;
    const int lane = tid & 63;
    const int wid  = tid >> 6;

    const int tiles = N_ / TI;              // 256 row-tiles per head
    const int head  = blockIdx.x / tiles;   // b*H + h
    const int it    = blockIdx.x % tiles;
    const int b     = head / H_;
    const int i0    = it * TI;

    const size_t hb = (size_t)head * N_ * D_;

    const float4* k4 = reinterpret_cast<const float4*>(k + hb);
    const float4* q4 = reinterpret_cast<const float4*>(q + hb + (size_t)i0 * D_);

    // ---------------- scores: sc[r][j] = (q_r . k_j)/8, masked ----------------
    #pragma unroll 1
    for (int jj = 0; jj < N_ / NT; ++jj) {
        const int j = tid + jj * NT;
        float4 kr[16];                       // full k row in regs (64 VGPR)
        #pragma unroll
        for (int d4 = 0; d4 < 16; ++d4) kr[d4] = k4[(size_t)j * 16 + d4];
        const int mv = mask[b * N_ + j];
        #pragma unroll 2
        for (int r = 0; r < TI; ++r) {
            float acc = 0.f;
            #pragma unroll
            for (int d4 = 0; d4 < 16; ++d4) {
                const float4 qv = q4[r * 16 + d4];   // block-uniform address
                acc += qv.x * kr[d4].x + qv.y * kr[d4].y
                     + qv.z * kr[d4].z + qv.w * kr[d4].w;
            }
            sc[r * N_ + j] = (mv == 0) ? -3.4e38f : acc * 0.125f;
        }
    }
    __syncthreads();

    // ---------------- softmax per row + write normalized attention ----------------
    #pragma unroll 1
    for (int r = 0; r < TI; ++r) {
        float m = -3.4e38f;
        for (int t = tid; t < N_; t += NT) m = fmaxf(m, sc[r * N_ + t]);
        #pragma unroll
        for (int off = 32; off > 0; off >>= 1) m = fmaxf(m, __shfl_xor(m, off, 64));
        if (lane == 0) red[wid] = m;
        __syncthreads();
        m = fmaxf(fmaxf(red[0], red[1]), fmaxf(red[2], red[3]));

        float s = 0.f;
        for (int t = tid; t < N_; t += NT) {
            const float e = __expf(sc[r * N_ + t] - m);
            sc[r * N_ + t] = e;
            s += e;
        }
        #pragma unroll
        for (int off = 32; off > 0; off >>= 1) s += __shfl_xor(s, off, 64);
        if (lane == 0) red[4 + wid] = s;
        __syncthreads();
        s = red[4] + red[5] + red[6] + red[7];

        const float inv = 1.0f / s;
        float4* a4 = reinterpret_cast<float4*>(attn + ((size_t)head * N_ + i0 + r) * N_);
        float4* s4 = reinterpret_cast<float4*>(&sc[r * N_]);
        for (int t = tid; t < N_ / 4; t += NT) {
            float4 p = s4[t];
            p.x *= inv; p.y *= inv; p.z *= inv; p.w *= inv;
            s4[t] = p;
            a4[t] = p;    // coalesced float4 store of attention row
        }
        __syncthreads();
    }

    // ---------------- PV: out[r][d] = sum_j p[r][j] * v[j][d] ----------------
    const int dgrp = tid & 15;          // float4 column group: d = dgrp*4..+3
    const int jgrp = tid >> 4;          // 16 j-groups of 128 keys each
    const float4* v4 = reinterpret_cast<const float4*>(v + hb);

    float4 o[TI];
    #pragma unroll
    for (int r = 0; r < TI; ++r) o[r] = make_float4(0.f, 0.f, 0.f, 0.f);

    #pragma unroll 1
    for (int jt = 0; jt < 128; jt += 4) {
        const int j = jgrp * 128 + jt;
        float4 vv[4];
        #pragma unroll
        for (int u = 0; u < 4; ++u) vv[u] = v4[(size_t)(j + u) * 16 + dgrp];
        #pragma unroll
        for (int r = 0; r < TI; ++r) {
            const float4 p = *reinterpret_cast<const float4*>(&sc[r * N_ + j]);
            o[r].x += p.x * vv[0].x + p.y * vv[1].x + p.z * vv[2].x + p.w * vv[3].x;
            o[r].y += p.x * vv[0].y + p.y * vv[1].y + p.z * vv[2].y + p.w * vv[3].y;
            o[r].z += p.x * vv[0].z + p.y * vv[1].z + p.z * vv[2].z + p.w * vv[3].z;
            o[r].w += p.x * vv[0].w + p.y * vv[1].w + p.z * vv[2].w + p.w * vv[3].w;
        }
    }
    __syncthreads();

    // cross-group reduction through LDS (reuse sc: 16*8*16 float4 = 32 KB)
    float4* po = reinterpret_cast<float4*>(sc);
    #pragma unroll
    for (int r = 0; r < TI; ++r) po[(jgrp * TI + r) * 16 + dgrp] = o[r];
    __syncthreads();

    if (tid < TI * 16) {
        const int r  = tid >> 4;
        const int dg = tid & 15;
        float4 acc = make_float4(0.f, 0.f, 0.f, 0.f);
        #pragma unroll
        for (int g = 0; g < 16; ++g) {
            const float4 t = po[(g * TI + r) * 16 + dg];
            acc.x += t.x; acc.y += t.y; acc.z += t.z; acc.w += t.w;
        }
        float4* o4 = reinterpret_cast<float4*>(out + ((size_t)head * N_ + i0 + r) * D_);
        o4[dg] = acc;
    }
}

extern "C" void kernel_launch(void* const* d_in, const int* in_sizes, int n_in,
                              void* d_out, int out_size, void* d_ws, size_t ws_size,
                              hipStream_t stream) {
    const float* q    = (const float*)d_in[0];
    const float* k    = (const float*)d_in[1];
    const float* v    = (const float*)d_in[2];
    const int*   mask = (const int*)d_in[3];

    float* out  = (float*)d_out;
    float* attn = out + (size_t)B_ * H_ * N_ * D_;   // outputs concatenated: (output, attention)

    dim3 grid(B_ * H_ * (N_ / TI));
    lg_attn<<<grid, NT, 0, stream>>>(q, k, v, mask, out, attn);
}

// Round 2
// 458.801 us; speedup vs baseline: 1.8093x; 1.8093x over previous
//
#include <hip/hip_runtime.h>

typedef __attribute__((ext_vector_type(8))) short short8;
typedef __attribute__((ext_vector_type(4))) float f32x4;

#define NHEADS 16
#define N_ 2048
#define D_ 64
#define ROWS 16          // q-rows per block
#define LDP 2056         // padded LDS row stride in ushort (2048 + 8)
#define NT 256

__device__ __forceinline__ unsigned short f2b(float f) {
    unsigned u = __float_as_uint(f);
    return (unsigned short)((u + 0x7FFFu + ((u >> 16) & 1u)) >> 16);   // RNE
}
__device__ __forceinline__ float b2f(unsigned short b) {
    return __uint_as_float(((unsigned)b) << 16);
}

// ---------------- prepass: fp32 -> bf16 flat ----------------
__global__ __launch_bounds__(NT)
void cvt_bf16_kernel(const float4* __restrict__ src, ushort4* __restrict__ dst, int n4)
{
    int i = blockIdx.x * NT + threadIdx.x;
    if (i < n4) {
        float4 v = src[i];
        ushort4 o;
        o.x = f2b(v.x); o.y = f2b(v.y); o.z = f2b(v.z); o.w = f2b(v.w);
        dst[i] = o;
    }
}

// ---------------- prepass: V (N,D) fp32 -> Vt (D,N) bf16 ----------------
__global__ __launch_bounds__(NT)
void vtrans_kernel(const float* __restrict__ v, unsigned short* __restrict__ vt)
{
    __shared__ float tile[64][65];
    const int head = blockIdx.x >> 5;           // 16 heads
    const int k0   = (blockIdx.x & 31) * 64;    // 32 k-chunks of 64
    const int tid  = threadIdx.x;

    {   // load 64x64 fp32 tile, coalesced
        const int i = tid >> 2;                 // k row within tile
        const int c = tid & 3;
        const float4* v4 = (const float4*)(v + ((size_t)(head * N_ + k0 + i)) * D_);
        #pragma unroll
        for (int u = 0; u < 4; ++u) {
            const int c4 = c + 4 * u;
            float4 val = v4[c4];
            tile[i][c4 * 4 + 0] = val.x;
            tile[i][c4 * 4 + 1] = val.y;
            tile[i][c4 * 4 + 2] = val.z;
            tile[i][c4 * 4 + 3] = val.w;
        }
    }
    __syncthreads();
    {   // write transposed bf16, coalesced along k
        const int d  = tid >> 2;
        const int kk = (tid & 3) * 16;
        unsigned short* dst = vt + ((size_t)(head * D_ + d)) * N_ + k0 + kk;
        #pragma unroll
        for (int m4 = 0; m4 < 4; ++m4) {
            ushort4 ov;
            ov.x = f2b(tile[kk + m4 * 4 + 0][d]);
            ov.y = f2b(tile[kk + m4 * 4 + 1][d]);
            ov.z = f2b(tile[kk + m4 * 4 + 2][d]);
            ov.w = f2b(tile[kk + m4 * 4 + 3][d]);
            *(ushort4*)(dst + m4 * 4) = ov;
        }
    }
}

// ---------------- main fused attention ----------------
__global__ __launch_bounds__(NT, 2)
void lg_attn(const unsigned short* __restrict__ Qb,
             const unsigned short* __restrict__ Kb,
             const unsigned short* __restrict__ Vt,
             const int* __restrict__ mask,
             float* __restrict__ out,
             float* __restrict__ attn)
{
    __shared__ unsigned short P[ROWS * LDP];   // 65792 B: exp / prob tile (bf16)
    __shared__ float wred[64];                 // per-wave row stats
    __shared__ float rowinv[ROWS];

    const int tid  = threadIdx.x;
    const int w    = tid >> 6;
    const int lane = tid & 63;
    const int quad = lane >> 4;
    const int l16  = lane & 15;

    const int head = blockIdx.x >> 7;          // 128 row-tiles per head
    const int it   = blockIdx.x & 127;
    const int i0   = it * ROWS;
    const int bidx = head >> 2;                // batch

    // persistent Q A-frags: A[m=l16][k=quad*8+j], two K=32 chunks over D=64
    const unsigned short* qrow = Qb + ((size_t)(head * N_ + i0 + l16)) * D_ + quad * 8;
    const short8 a0 = *(const short8*)qrow;
    const short8 a1 = *(const short8*)(qrow + 32);

    const unsigned short* kbase = Kb + (size_t)head * N_ * D_;
    const int* mrow = mask + bidx * N_;

    // ---- pass A: row max (scores via MFMA, not stored) ----
    float bm[4];
    {
        float m4[4] = {-3.4e38f, -3.4e38f, -3.4e38f, -3.4e38f};
        for (int t = 0; t < 32; ++t) {
            const int j0 = (w + 4 * t) * 16;
            const unsigned short* krow = kbase + (size_t)(j0 + l16) * D_ + quad * 8;
            short8 b0 = *(const short8*)krow;
            short8 b1 = *(const short8*)(krow + 32);
            f32x4 c = {0.f, 0.f, 0.f, 0.f};
            c = __builtin_amdgcn_mfma_f32_16x16x32_bf16(a0, b0, c, 0, 0, 0);
            c = __builtin_amdgcn_mfma_f32_16x16x32_bf16(a1, b1, c, 0, 0, 0);
            const int mv = mrow[j0 + l16];
            #pragma unroll
            for (int r = 0; r < 4; ++r) {
                float s = (mv == 0) ? -3.4e38f : c[r] * 0.125f;
                m4[r] = fmaxf(m4[r], s);
            }
        }
        #pragma unroll
        for (int r = 0; r < 4; ++r) {
            #pragma unroll
            for (int off = 1; off < 16; off <<= 1)
                m4[r] = fmaxf(m4[r], __shfl_xor(m4[r], off, 64));
        }
        if (l16 == 0) {
            #pragma unroll
            for (int r = 0; r < 4; ++r) wred[w * 16 + quad * 4 + r] = m4[r];
        }
        __syncthreads();
        #pragma unroll
        for (int r = 0; r < 4; ++r) {
            const int row = quad * 4 + r;
            bm[r] = fmaxf(fmaxf(wred[row], wred[16 + row]),
                          fmaxf(wred[32 + row], wred[48 + row]));
        }
        __syncthreads();   // before wred reuse
    }

    // ---- pass B: recompute scores, exp, store bf16 to LDS, row sums ----
    {
        float s4[4] = {0.f, 0.f, 0.f, 0.f};
        for (int t = 0; t < 32; ++t) {
            const int j0 = (w + 4 * t) * 16;
            const unsigned short* krow = kbase + (size_t)(j0 + l16) * D_ + quad * 8;
            short8 b0 = *(const short8*)krow;
            short8 b1 = *(const short8*)(krow + 32);
            f32x4 c = {0.f, 0.f, 0.f, 0.f};
            c = __builtin_amdgcn_mfma_f32_16x16x32_bf16(a0, b0, c, 0, 0, 0);
            c = __builtin_amdgcn_mfma_f32_16x16x32_bf16(a1, b1, c, 0, 0, 0);
            const int mv = mrow[j0 + l16];
            #pragma unroll
            for (int r = 0; r < 4; ++r) {
                float s = (mv == 0) ? -3.4e38f : c[r] * 0.125f;
                float p = __expf(s - bm[r]);
                s4[r] += p;
                P[(quad * 4 + r) * LDP + j0 + l16] = f2b(p);
            }
        }
        #pragma unroll
        for (int r = 0; r < 4; ++r) {
            #pragma unroll
            for (int off = 1; off < 16; off <<= 1)
                s4[r] += __shfl_xor(s4[r], off, 64);
        }
        if (l16 == 0) {
            #pragma unroll
            for (int r = 0; r < 4; ++r) wred[w * 16 + quad * 4 + r] = s4[r];
        }
        __syncthreads();
        if (w == 0 && l16 == 0) {
            #pragma unroll
            for (int r = 0; r < 4; ++r) {
                const int row = quad * 4 + r;
                const float bs = wred[row] + wred[16 + row] + wred[32 + row] + wred[48 + row];
                rowinv[row] = 1.0f / bs;
            }
        }
        __syncthreads();
    }

    // ---- pass C: normalize; stream attention (fp32, coalesced); P -> normalized bf16 ----
    for (int r = 0; r < ROWS; ++r) {
        const float inv = rowinv[r];
        float4* arow = (float4*)(attn + ((size_t)(head * N_ + i0 + r)) * N_);
        for (int c4 = tid; c4 < N_ / 4; c4 += NT) {
            ushort4 tv = *(ushort4*)&P[r * LDP + c4 * 4];
            float4 f;
            f.x = b2f(tv.x) * inv;
            f.y = b2f(tv.y) * inv;
            f.z = b2f(tv.z) * inv;
            f.w = b2f(tv.w) * inv;
            arow[c4] = f;
            tv.x = f2b(f.x); tv.y = f2b(f.y); tv.z = f2b(f.z); tv.w = f2b(f.w);
            *(ushort4*)&P[r * LDP + c4 * 4] = tv;
        }
    }
    __syncthreads();

    // ---- pass D: O = P(16xN) * V(NxD) via MFMA; wave w owns d-cols n0..n0+15 ----
    {
        const int n0 = w * 16;
        const unsigned short* vbase =
            Vt + ((size_t)(head * D_ + n0 + l16)) * N_ + quad * 8;
        f32x4 o = {0.f, 0.f, 0.f, 0.f};
        for (int kc = 0; kc < 64; ++kc) {
            short8 ap = *(short8*)&P[l16 * LDP + kc * 32 + quad * 8];
            short8 bv = *(const short8*)(vbase + kc * 32);
            o = __builtin_amdgcn_mfma_f32_16x16x32_bf16(ap, bv, o, 0, 0, 0);
        }
        #pragma unroll
        for (int r = 0; r < 4; ++r)
            out[((size_t)(head * N_ + i0 + quad * 4 + r)) * D_ + n0 + l16] = o[r];
    }
}

extern "C" void kernel_launch(void* const* d_in, const int* in_sizes, int n_in,
                              void* d_out, int out_size, void* d_ws, size_t ws_size,
                              hipStream_t stream) {
    const float* q    = (const float*)d_in[0];
    const float* k    = (const float*)d_in[1];
    const float* v    = (const float*)d_in[2];
    const int*   mask = (const int*)d_in[3];

    float* out  = (float*)d_out;
    float* attn = out + (size_t)NHEADS * N_ * D_;   // (output, attention) concatenated

    const size_t elems = (size_t)NHEADS * N_ * D_;  // 2,097,152 per tensor
    unsigned short* Qb = (unsigned short*)d_ws;
    unsigned short* Kb = Qb + elems;
    unsigned short* Vt = Kb + elems;

    const int n4 = (int)(elems / 4);
    const int cblocks = (n4 + NT - 1) / NT;
    cvt_bf16_kernel<<<cblocks, NT, 0, stream>>>((const float4*)q, (ushort4*)Qb, n4);
    cvt_bf16_kernel<<<cblocks, NT, 0, stream>>>((const float4*)k, (ushort4*)Kb, n4);
    vtrans_kernel<<<NHEADS * 32, NT, 0, stream>>>(v, Vt);

    lg_attn<<<NHEADS * 128, NT, 0, stream>>>(Qb, Kb, Vt, mask, out, attn);
}

// Round 4
// 385.897 us; speedup vs baseline: 2.1511x; 1.1889x over previous
//
#include <hip/hip_runtime.h>

typedef __attribute__((ext_vector_type(8))) short short8;
typedef __attribute__((ext_vector_type(4))) float f32x4;

#define NHEADS 16
#define N_ 2048
#define D_ 64
#define ROWS 16          // q-rows per block
#define LDP 2056         // padded LDS row stride in ushort (2048 + 8)
#define NT 256

__device__ __forceinline__ unsigned short f2b(float f) {
    unsigned u = __float_as_uint(f);
    return (unsigned short)((u + 0x7FFFu + ((u >> 16) & 1u)) >> 16);   // RNE
}
__device__ __forceinline__ float b2f(unsigned short b) {
    return __uint_as_float(((unsigned)b) << 16);
}

// ---------------- prepass: fp32 -> bf16 flat ----------------
__global__ __launch_bounds__(NT)
void cvt_bf16_kernel(const float4* __restrict__ src, ushort4* __restrict__ dst, int n4)
{
    int i = blockIdx.x * NT + threadIdx.x;
    if (i < n4) {
        float4 v = src[i];
        ushort4 o;
        o.x = f2b(v.x); o.y = f2b(v.y); o.z = f2b(v.z); o.w = f2b(v.w);
        dst[i] = o;
    }
}

// ---------------- prepass: V (N,D) fp32 -> Vt (D,N) bf16 ----------------
__global__ __launch_bounds__(NT)
void vtrans_kernel(const float* __restrict__ v, unsigned short* __restrict__ vt)
{
    __shared__ float tile[64][65];
    const int head = blockIdx.x >> 5;           // 16 heads
    const int k0   = (blockIdx.x & 31) * 64;    // 32 k-chunks of 64
    const int tid  = threadIdx.x;

    {   // load 64x64 fp32 tile, coalesced
        const int i = tid >> 2;
        const int c = tid & 3;
        const float4* v4 = (const float4*)(v + ((size_t)(head * N_ + k0 + i)) * D_);
        #pragma unroll
        for (int u = 0; u < 4; ++u) {
            const int c4 = c + 4 * u;
            float4 val = v4[c4];
            tile[i][c4 * 4 + 0] = val.x;
            tile[i][c4 * 4 + 1] = val.y;
            tile[i][c4 * 4 + 2] = val.z;
            tile[i][c4 * 4 + 3] = val.w;
        }
    }
    __syncthreads();
    {   // write transposed bf16, coalesced along k
        const int d  = tid >> 2;
        const int kk = (tid & 3) * 16;
        unsigned short* dst = vt + ((size_t)(head * D_ + d)) * N_ + k0 + kk;
        #pragma unroll
        for (int m4 = 0; m4 < 4; ++m4) {
            ushort4 ov;
            ov.x = f2b(tile[kk + m4 * 4 + 0][d]);
            ov.y = f2b(tile[kk + m4 * 4 + 1][d]);
            ov.z = f2b(tile[kk + m4 * 4 + 2][d]);
            ov.w = f2b(tile[kk + m4 * 4 + 3][d]);
            *(ushort4*)(dst + m4 * 4) = ov;
        }
    }
}

// ---------------- main fused attention (single K-sweep, scores in VGPRs) ----------------
__global__ __launch_bounds__(NT, 2)
void lg_attn(const unsigned short* __restrict__ Qb,
             const unsigned short* __restrict__ Kb,
             const unsigned short* __restrict__ Vt,
             const int* __restrict__ mask,
             float* __restrict__ out,
             float* __restrict__ attn)
{
    __shared__ unsigned short P[ROWS * LDP];   // 65792 B: unnormalized exp (bf16)
    __shared__ float wred[128];                // [0:64) max slots, [64:128) sum slots

    const int tid  = threadIdx.x;
    const int w    = tid >> 6;
    const int lane = tid & 63;
    const int quad = lane >> 4;
    const int l16  = lane & 15;

    const int head = blockIdx.x >> 7;          // 128 row-tiles per head
    const int it   = blockIdx.x & 127;
    const int i0   = it * ROWS;
    const int bidx = head >> 2;

    // persistent Q A-frags: A[m=l16][k=quad*8+j], two K=32 chunks over D=64
    const unsigned short* qrow = Qb + ((size_t)(head * N_ + i0 + l16)) * D_ + quad * 8;
    const short8 a0 = *(const short8*)qrow;
    const short8 a1 = *(const short8*)(qrow + 32);

    const unsigned short* kbase = Kb + (size_t)head * N_ * D_;
    const int* mrow = mask + bidx * N_;

    // ---- single sweep: raw scores via MFMA into register stash ----
    f32x4 c[32];
    #pragma unroll
    for (int tc = 0; tc < 4; ++tc) {
        #pragma unroll
        for (int ti = 0; ti < 8; ++ti) {
            const int t  = tc * 8 + ti;
            const int j0 = (w + 4 * t) * 16;
            const unsigned short* krow = kbase + (size_t)(j0 + l16) * D_ + quad * 8;
            short8 b0 = *(const short8*)krow;
            short8 b1 = *(const short8*)(krow + 32);
            f32x4 cc = {0.f, 0.f, 0.f, 0.f};
            cc = __builtin_amdgcn_mfma_f32_16x16x32_bf16(a0, b0, cc, 0, 0, 0);
            cc = __builtin_amdgcn_mfma_f32_16x16x32_bf16(a1, b1, cc, 0, 0, 0);
            const int mv = mrow[j0 + l16];
            #pragma unroll
            for (int r = 0; r < 4; ++r)
                c[t][r] = (mv == 0) ? -3.4e38f : cc[r];   // raw score (scale folded into exp)
        }
        __builtin_amdgcn_sched_barrier(0);   // bound in-flight loads: protect score stash from spills
    }

    // ---- row max (registers -> lanes -> waves) ----
    float bm[4];
    {
        float m4[4] = {-3.4e38f, -3.4e38f, -3.4e38f, -3.4e38f};
        #pragma unroll
        for (int t = 0; t < 32; ++t)
            #pragma unroll
            for (int r = 0; r < 4; ++r) m4[r] = fmaxf(m4[r], c[t][r]);
        #pragma unroll
        for (int r = 0; r < 4; ++r)
            #pragma unroll
            for (int off = 1; off < 16; off <<= 1)
                m4[r] = fmaxf(m4[r], __shfl_xor(m4[r], off, 64));
        if (l16 == 0) {
            #pragma unroll
            for (int r = 0; r < 4; ++r) wred[w * 16 + quad * 4 + r] = m4[r];
        }
        __syncthreads();
        #pragma unroll
        for (int r = 0; r < 4; ++r) {
            const int row = quad * 4 + r;
            bm[r] = fmaxf(fmaxf(wred[row], wred[16 + row]),
                          fmaxf(wred[32 + row], wred[48 + row]));
        }
    }

    // ---- exp from registers, row sums, bf16 scatter to LDS ----
    {
        float s4[4] = {0.f, 0.f, 0.f, 0.f};
        #pragma unroll
        for (int t = 0; t < 32; ++t) {
            const int j0 = (w + 4 * t) * 16;
            #pragma unroll
            for (int r = 0; r < 4; ++r) {
                const float p = __expf((c[t][r] - bm[r]) * 0.125f);
                s4[r] += p;
                P[(quad * 4 + r) * LDP + j0 + l16] = f2b(p);
            }
        }
        #pragma unroll
        for (int r = 0; r < 4; ++r)
            #pragma unroll
            for (int off = 1; off < 16; off <<= 1)
                s4[r] += __shfl_xor(s4[r], off, 64);
        if (l16 == 0) {
            #pragma unroll
            for (int r = 0; r < 4; ++r) wred[64 + w * 16 + quad * 4 + r] = s4[r];
        }
        __syncthreads();   // covers sum slots AND P scatter completion
    }

    // ---- normalize + stream attention out (coalesced, nontemporal) ----
    {
        const size_t abase = (size_t)(head * N_ + i0) * N_;
        #pragma unroll 1
        for (int r = 0; r < ROWS; ++r) {
            const float s = wred[64 + r] + wred[80 + r] + wred[96 + r] + wred[112 + r];
            const float inv = 1.0f / s;
            f32x4* arow = (f32x4*)(attn + abase + (size_t)r * N_);
            #pragma unroll
            for (int u = 0; u < 2; ++u) {
                const int c4 = tid + u * NT;
                ushort4 tv = *(ushort4*)&P[r * LDP + c4 * 4];
                f32x4 f;
                f.x = b2f(tv.x) * inv;
                f.y = b2f(tv.y) * inv;
                f.z = b2f(tv.z) * inv;
                f.w = b2f(tv.w) * inv;
                __builtin_nontemporal_store(f, &arow[c4]);
            }
        }
    }

    // ---- PV on unnormalized P; fold 1/l into epilogue ----
    {
        const int n0 = w * 16;
        const unsigned short* vbase =
            Vt + ((size_t)(head * D_ + n0 + l16)) * N_ + quad * 8;
        f32x4 o = {0.f, 0.f, 0.f, 0.f};
        #pragma unroll 4
        for (int kc = 0; kc < 64; ++kc) {
            short8 ap = *(short8*)&P[l16 * LDP + kc * 32 + quad * 8];
            short8 bv = *(const short8*)(vbase + kc * 32);
            o = __builtin_amdgcn_mfma_f32_16x16x32_bf16(ap, bv, o, 0, 0, 0);
        }
        #pragma unroll
        for (int r = 0; r < 4; ++r) {
            const int row = quad * 4 + r;
            const float s = wred[64 + row] + wred[80 + row] + wred[96 + row] + wred[112 + row];
            out[((size_t)(head * N_ + i0 + row)) * D_ + n0 + l16] = o[r] / s;
        }
    }
}

extern "C" void kernel_launch(void* const* d_in, const int* in_sizes, int n_in,
                              void* d_out, int out_size, void* d_ws, size_t ws_size,
                              hipStream_t stream) {
    const float* q    = (const float*)d_in[0];
    const float* k    = (const float*)d_in[1];
    const float* v    = (const float*)d_in[2];
    const int*   mask = (const int*)d_in[3];

    float* out  = (float*)d_out;
    float* attn = out + (size_t)NHEADS * N_ * D_;   // (output, attention) concatenated

    const size_t elems = (size_t)NHEADS * N_ * D_;  // 2,097,152 per tensor
    unsigned short* Qb = (unsigned short*)d_ws;
    unsigned short* Kb = Qb + elems;
    unsigned short* Vt = Kb + elems;

    const int n4 = (int)(elems / 4);
    const int cblocks = (n4 + NT - 1) / NT;
    cvt_bf16_kernel<<<cblocks, NT, 0, stream>>>((const float4*)q, (ushort4*)Qb, n4);
    cvt_bf16_kernel<<<cblocks, NT, 0, stream>>>((const float4*)k, (ushort4*)Kb, n4);
    vtrans_kernel<<<NHEADS * 32, NT, 0, stream>>>(v, Vt);

    lg_attn<<<NHEADS * 128, NT, 0, stream>>>(Qb, Kb, Vt, mask, out, attn);
}